// Round 2
// baseline (2459.580 us; speedup 1.0000x reference)
//
#include <hip/hip_runtime.h>

// GRU_43387759624777 — Round 2: fp32 scan, fixed register budget.
// R1 post-mortem: __launch_bounds__(256) made the compiler target 4 waves/SIMD
// (112 arch VGPRs) and spill the 192 weight floats to AGPRs -> ~192 extra
// v_accvgpr_read per step (measured ~1380 issue-cyc/step vs 540 modeled).
// Fix: one wave per block + __launch_bounds__(64,1) -> full 512-VGPR budget,
// weights stay in arch VGPRs. 2 waves/SIMD resident is plenty (issue-bound).
//
// Layout: one wave per batch row; lane i owns hidden unit i. Per step:
// 64 v_readlane broadcasts of h + 192 FMAs + gate math.

#define HID 64
#define SEQ 1024
#define BATCH 4096

__device__ __forceinline__ float bcast(float v, int srclane) {
  return __int_as_float(__builtin_amdgcn_readlane(__float_as_int(v), srclane));
}

__device__ __forceinline__ float sigm(float v) {
  return 1.0f / (1.0f + __expf(-v));
}

__device__ __forceinline__ float tanh_fast(float v) {
  // tanh(x) = 1 - 2/(exp(2x)+1)
  return 1.0f - 2.0f / (__expf(2.0f * v) + 1.0f);
}

__global__ __launch_bounds__(64, 1) void gru_scan_fp32(
    const float* __restrict__ x,     // [B, T] (INPUT=1 folded)
    const float* __restrict__ w_ih,  // [192, 1]
    const float* __restrict__ w_hh,  // [192, 64]
    const float* __restrict__ b_ih,  // [192]
    const float* __restrict__ b_hh,  // [192]
    const float* __restrict__ w1,    // [32, 64]
    const float* __restrict__ b1,    // [32]
    const float* __restrict__ w2,    // [16, 32]
    const float* __restrict__ b2,    // [16]
    const float* __restrict__ w3,    // [1, 16]
    const float* __restrict__ b3,    // [1]
    float* __restrict__ out)         // [B, 1]
{
  const int lane = threadIdx.x;      // 0..63, one wave per block
  const int row  = blockIdx.x;       // batch row, grid = 4096

  // ---- recurrent weights into VGPRs (rows lane, 64+lane, 128+lane)
  float wr[HID], wz[HID], wn[HID];
  const float4* whh4 = reinterpret_cast<const float4*>(w_hh);
  #pragma unroll
  for (int j4 = 0; j4 < HID / 4; ++j4) {
    float4 a = whh4[(0   + lane) * (HID / 4) + j4];
    float4 b = whh4[(64  + lane) * (HID / 4) + j4];
    float4 c = whh4[(128 + lane) * (HID / 4) + j4];
    wr[4*j4+0] = a.x; wr[4*j4+1] = a.y; wr[4*j4+2] = a.z; wr[4*j4+3] = a.w;
    wz[4*j4+0] = b.x; wz[4*j4+1] = b.y; wz[4*j4+2] = b.z; wz[4*j4+3] = b.w;
    wn[4*j4+0] = c.x; wn[4*j4+1] = c.y; wn[4*j4+2] = c.z; wn[4*j4+3] = c.w;
  }

  // input-projection constants for this lane's three gates
  const float wir = w_ih[lane];
  const float wiz = w_ih[64 + lane];
  const float win = w_ih[128 + lane];
  // r,z biases combine (b_ih + b_hh); n-gate's b_hh must stay inside r*(...)
  const float br   = b_ih[lane]       + b_hh[lane];
  const float bz   = b_ih[64 + lane]  + b_hh[64 + lane];
  const float bn_i = b_ih[128 + lane];
  const float bn_h = b_hh[128 + lane];

  float h = 0.0f;
  const float* xrow = x + (size_t)row * SEQ;

  for (int tb = 0; tb < SEQ / 64; ++tb) {
    // coalesced: each lane grabs one timestep of this row's input
    float xpack = xrow[tb * 64 + lane];
    #pragma unroll 1
    for (int s = 0; s < 64; ++s) {
      float xt = bcast(xpack, s);  // dynamic-but-uniform lane index
      float gr = 0.0f, gz = 0.0f, gn = 0.0f;
      #pragma unroll
      for (int j = 0; j < HID; ++j) {
        float hj = bcast(h, j);    // static lane index after unroll
        gr = __fmaf_rn(wr[j], hj, gr);
        gz = __fmaf_rn(wz[j], hj, gz);
        gn = __fmaf_rn(wn[j], hj, gn);
      }
      float r = sigm(gr + __fmaf_rn(xt, wir, br));
      float z = sigm(gz + __fmaf_rn(xt, wiz, bz));
      float n = tanh_fast(__fmaf_rn(xt, win, bn_i) + r * (gn + bn_h));
      h = n + z * (h - n);         // (1-z)*n + z*h
    }
  }

  // ---- MLP head: 64 -> 32 -> 16 -> 1 (leaky relu 0.01 on first two)
  __shared__ float hb[HID];
  __shared__ float y1b[32];
  __shared__ float y2b[16];

  hb[lane] = h;
  __syncthreads();

  if (lane < 32) {
    float a = b1[lane];
    #pragma unroll
    for (int j = 0; j < 64; ++j) a = __fmaf_rn(w1[lane * 64 + j], hb[j], a);
    y1b[lane] = (a > 0.0f) ? a : 0.01f * a;
  }
  __syncthreads();

  if (lane < 16) {
    float a = b2[lane];
    #pragma unroll
    for (int j = 0; j < 32; ++j) a = __fmaf_rn(w2[lane * 32 + j], y1b[j], a);
    y2b[lane] = (a > 0.0f) ? a : 0.01f * a;
  }
  __syncthreads();

  if (lane == 0) {
    float a = b3[0];
    #pragma unroll
    for (int j = 0; j < 16; ++j) a = __fmaf_rn(w3[j], y2b[j], a);
    out[row] = a;
  }
}

extern "C" void kernel_launch(void* const* d_in, const int* in_sizes, int n_in,
                              void* d_out, int out_size, void* d_ws, size_t ws_size,
                              hipStream_t stream) {
  const float* x    = (const float*)d_in[0];
  const float* w_ih = (const float*)d_in[1];
  const float* w_hh = (const float*)d_in[2];
  const float* b_ih = (const float*)d_in[3];
  const float* b_hh = (const float*)d_in[4];
  const float* w1   = (const float*)d_in[5];
  const float* b1   = (const float*)d_in[6];
  const float* w2   = (const float*)d_in[7];
  const float* b2   = (const float*)d_in[8];
  const float* w3   = (const float*)d_in[9];
  const float* b3   = (const float*)d_in[10];
  float* out = (float*)d_out;

  dim3 grid(BATCH);   // one wave (one row) per block
  dim3 block(64);
  hipLaunchKernelGGL(gru_scan_fp32, grid, block, 0, stream,
                     x, w_ih, w_hh, b_ih, b_hh, w1, b1, w2, b2, w3, b3, out);
}

// Round 3
// 823.946 us; speedup vs baseline: 2.9851x; 2.9851x over previous
//
#include <hip/hip_runtime.h>

// GRU_43387759624777 — Round 3: MFMA block-scan, split-bf16 (hi+lo) recurrence.
//
// R2 post-mortem: fp32 VALU floor is 656 us (103 GFLOP / 157 TF); allocator
// keeps per-lane weight arrays in AGPRs with ~2.5x instruction bloat -> 2580 us.
// Switch to matrix cores: gh[16x192] = h[16x64] @ w_hh^T per step via
// mfma_f32_16x16x32_bf16. Accuracy: W and h each split into bf16 hi+lo;
// product = Whi*hhi + Whi*hlo + Wlo*hhi (error ~2^-18/step, fp32-grade).
//
// Block = 16 batch rows x 256 threads (4 waves); 256 blocks = 1 block/CU.
// Wave w owns N-tiles {3w,3w+1,3w+2} of the 12 (192 = 3 gates x 64 units);
// W fragments in registers (48 VGPRs), loaded once. h: registers (4/lane in
// elementwise role) -> LDS bf16 A-fragments -> MFMA. Gates fp32 via LDS.
// Fragment maps (verified m89/m120): A/B: [dim0=lane&15][k=(lane>>4)*8+j];
// C/D: col=lane&15, row=(lane>>4)*4+reg.

#define HID 64
#define SEQ 1024
#define BATCH 4096
#define ROWS 16

typedef __attribute__((ext_vector_type(8))) short short8;
typedef __attribute__((ext_vector_type(4))) float f32x4;

__device__ __forceinline__ short f2bf(float f) {
  unsigned u = __float_as_uint(f);
  u += 0x7fffu + ((u >> 16) & 1u);   // RNE
  return (short)(u >> 16);
}
__device__ __forceinline__ float bf2f(short s) {
  return __uint_as_float(((unsigned)(unsigned short)s) << 16);
}
__device__ __forceinline__ float rcp_fast(float x) { return __builtin_amdgcn_rcpf(x); }

__global__ __launch_bounds__(256, 1) void gru_mfma(
    const float* __restrict__ x,     // [B, T]
    const float* __restrict__ w_ih,  // [192, 1]
    const float* __restrict__ w_hh,  // [192, 64]
    const float* __restrict__ b_ih,  // [192]
    const float* __restrict__ b_hh,  // [192]
    const float* __restrict__ w1,    // [32, 64]
    const float* __restrict__ b1,    // [32]
    const float* __restrict__ w2,    // [16, 32]
    const float* __restrict__ b2,    // [16]
    const float* __restrict__ w3,    // [1, 16]
    const float* __restrict__ b3,    // [1]
    float* __restrict__ out)         // [B, 1]
{
  const int L  = threadIdx.x;        // 0..255
  const int l  = L & 63;             // lane in wave
  const int wv = L >> 6;             // wave 0..3
  const int r0 = blockIdx.x * ROWS;  // first batch row of this block

  // ---------------- LDS ----------------
  __shared__ __align__(16) short hfrag[2][2][64][8]; // [hi/lo][kt][lane][j] bf16 A-frags (4 KB)
  __shared__ float gbuf[3][ROWS][68];                // [gate][row][unit] fp32 gate pre-acts
  __shared__ float xbuf[ROWS][68];                   // 64-step x chunk (reused for h at end)
  __shared__ float ybuf1[ROWS][36];
  __shared__ float ybuf2[ROWS][20];

  // ---------------- W fragments (registers, once) ----------------
  // B-frag for tile nt, kt: lane holds w_hh[nt*16 + (l&15)][kt*32 + (l>>4)*8 + j]
  short8 bhi[3][2], blo[3][2];
  {
    const int n0 = l & 15, q = l >> 4;
    #pragma unroll
    for (int nt3 = 0; nt3 < 3; ++nt3) {
      const int c = (wv * 3 + nt3) * 16 + n0;
      #pragma unroll
      for (int kt = 0; kt < 2; ++kt) {
        const float* p = w_hh + c * HID + kt * 32 + q * 8;
        f32x4 p0 = *(const f32x4*)p;
        f32x4 p1 = *(const f32x4*)(p + 4);
        float vals[8] = {p0[0], p0[1], p0[2], p0[3], p1[0], p1[1], p1[2], p1[3]};
        short8 hi8, lo8;
        #pragma unroll
        for (int j = 0; j < 8; ++j) {
          short h8 = f2bf(vals[j]);
          hi8[j] = h8;
          lo8[j] = f2bf(vals[j] - bf2f(h8));
        }
        bhi[nt3][kt] = hi8;
        blo[nt3][kt] = lo8;
      }
    }
  }

  // ---------------- per-lane elementwise constants ----------------
  // Lane (m = L>>4, g = L&15) owns units u = 4g..4g+3 of row m, every step.
  const int m = L >> 4;
  const int g = L & 15;
  float wir[4], wiz[4], win[4], br[4], bz[4], bni[4], bnh[4], h[4];
  #pragma unroll
  for (int i = 0; i < 4; ++i) {
    const int u = 4 * g + i;
    wir[i] = w_ih[u]; wiz[i] = w_ih[64 + u]; win[i] = w_ih[128 + u];
    br[i]  = b_ih[u] + b_hh[u];
    bz[i]  = b_ih[64 + u] + b_hh[64 + u];
    bni[i] = b_ih[128 + u];
    bnh[i] = b_hh[128 + u];
    h[i]   = 0.0f;
  }

  // hfrag write target for this lane (same every step):
  // u=4g+i -> kt=g>>3, quad=(g>>1)&3, j=4(g&1)+i, dest lane = m+16*quad
  short* hdst = &hfrag[0][g >> 3][m + 16 * ((g >> 1) & 3)][4 * (g & 1)];
  short* ldst = &hfrag[1][g >> 3][m + 16 * ((g >> 1) & 3)][4 * (g & 1)];

  // zero-init hfrag (h0 = 0)
  for (int i = L; i < 2 * 2 * 64 * 8 / 2; i += 256) ((unsigned*)hfrag)[i] = 0u;

  const float* xblk = x + (size_t)r0 * SEQ;

  // ---------------- scan ----------------
  for (int tb = 0; tb < SEQ / 64; ++tb) {
    __syncthreads();  // xbuf safe to overwrite
    {
      const int row = L >> 4, tq = L & 15;
      f32x4 v = *(const f32x4*)(xblk + (size_t)row * SEQ + tb * 64 + tq * 4);
      *(f32x4*)&xbuf[row][tq * 4] = v;
    }
    for (int s = 0; s < 64; ++s) {
      __syncthreads();  // hfrag (and xbuf) ready

      // ---- MFMA phase: gh = [hhi+hlo] @ [Whi+Wlo]^T (3 terms) ----
      short8 ahi0 = *(const short8*)&hfrag[0][0][l][0];
      short8 ahi1 = *(const short8*)&hfrag[0][1][l][0];
      short8 alo0 = *(const short8*)&hfrag[1][0][l][0];
      short8 alo1 = *(const short8*)&hfrag[1][1][l][0];
      #pragma unroll
      for (int nt3 = 0; nt3 < 3; ++nt3) {
        f32x4 a = {0.f, 0.f, 0.f, 0.f};
        a = __builtin_amdgcn_mfma_f32_16x16x32_bf16(ahi0, bhi[nt3][0], a, 0, 0, 0);
        a = __builtin_amdgcn_mfma_f32_16x16x32_bf16(ahi1, bhi[nt3][1], a, 0, 0, 0);
        a = __builtin_amdgcn_mfma_f32_16x16x32_bf16(alo0, bhi[nt3][0], a, 0, 0, 0);
        a = __builtin_amdgcn_mfma_f32_16x16x32_bf16(alo1, bhi[nt3][1], a, 0, 0, 0);
        a = __builtin_amdgcn_mfma_f32_16x16x32_bf16(ahi0, blo[nt3][0], a, 0, 0, 0);
        a = __builtin_amdgcn_mfma_f32_16x16x32_bf16(ahi1, blo[nt3][1], a, 0, 0, 0);
        const int ntg  = wv * 3 + nt3;
        const int gate = ntg >> 2;                    // uniform per tile
        const int u    = ((ntg & 3) << 4) + (l & 15); // col within gate
        #pragma unroll
        for (int r = 0; r < 4; ++r)
          gbuf[gate][(l >> 4) * 4 + r][u] = a[r];
      }
      __syncthreads();  // gbuf ready; hfrag reads done

      // ---- elementwise phase: gates + h update (h stays in registers) ----
      const float xt = xbuf[m][s];
      f32x4 gr4 = *(const f32x4*)&gbuf[0][m][4 * g];
      f32x4 gz4 = *(const f32x4*)&gbuf[1][m][4 * g];
      f32x4 gn4 = *(const f32x4*)&gbuf[2][m][4 * g];
      unsigned hp[2], lp[2];
      #pragma unroll
      for (int i = 0; i < 4; ++i) {
        float rpre = gr4[i] + __fmaf_rn(xt, wir[i], br[i]);
        float r    = rcp_fast(1.0f + __expf(-rpre));
        float zpre = gz4[i] + __fmaf_rn(xt, wiz[i], bz[i]);
        float z    = rcp_fast(1.0f + __expf(-zpre));
        float npre = __fmaf_rn(r, gn4[i] + bnh[i], __fmaf_rn(xt, win[i], bni[i]));
        float n    = 1.0f - 2.0f * rcp_fast(__expf(2.0f * npre) + 1.0f);
        h[i] = __fmaf_rn(z, h[i] - n, n);
        short hi = f2bf(h[i]);
        short lo = f2bf(h[i] - bf2f(hi));
        ((unsigned short*)hp)[i] = (unsigned short)hi;
        ((unsigned short*)lp)[i] = (unsigned short)lo;
      }
      *(uint2*)hdst = make_uint2(hp[0], hp[1]);
      *(uint2*)ldst = make_uint2(lp[0], lp[1]);
    }
  }

  // ---------------- MLP head: 64 -> 32 -> 16 -> 1 ----------------
  __syncthreads();
  *(f32x4*)&xbuf[m][4 * g] = (f32x4){h[0], h[1], h[2], h[3]};  // h fp32 -> LDS
  __syncthreads();

  #pragma unroll
  for (int rep = 0; rep < 2; ++rep) {           // 16 rows x 32 outs = 512 tasks
    const int o = (L & 15) + 16 * rep;
    const int row = L >> 4;
    float a = b1[o];
    #pragma unroll
    for (int j4 = 0; j4 < 16; ++j4) {
      f32x4 wv4 = *(const f32x4*)&w1[o * 64 + 4 * j4];
      f32x4 hv  = *(const f32x4*)&xbuf[row][4 * j4];
      a += wv4[0] * hv[0] + wv4[1] * hv[1] + wv4[2] * hv[2] + wv4[3] * hv[3];
    }
    ybuf1[row][o] = (a > 0.0f) ? a : 0.01f * a;
  }
  __syncthreads();

  {
    const int o = L & 15;
    const int row = L >> 4;
    float a = b2[o];
    #pragma unroll
    for (int j4 = 0; j4 < 8; ++j4) {
      f32x4 wv4 = *(const f32x4*)&w2[o * 32 + 4 * j4];
      f32x4 yv  = *(const f32x4*)&ybuf1[row][4 * j4];
      a += wv4[0] * yv[0] + wv4[1] * yv[1] + wv4[2] * yv[2] + wv4[3] * yv[3];
    }
    ybuf2[row][o] = (a > 0.0f) ? a : 0.01f * a;
  }
  __syncthreads();

  if (L < ROWS) {
    float a = b3[0];
    #pragma unroll
    for (int j = 0; j < 16; ++j) a = __fmaf_rn(w3[j], ybuf2[L][j], a);
    out[r0 + L] = a;
  }
}

extern "C" void kernel_launch(void* const* d_in, const int* in_sizes, int n_in,
                              void* d_out, int out_size, void* d_ws, size_t ws_size,
                              hipStream_t stream) {
  const float* x    = (const float*)d_in[0];
  const float* w_ih = (const float*)d_in[1];
  const float* w_hh = (const float*)d_in[2];
  const float* b_ih = (const float*)d_in[3];
  const float* b_hh = (const float*)d_in[4];
  const float* w1   = (const float*)d_in[5];
  const float* b1   = (const float*)d_in[6];
  const float* w2   = (const float*)d_in[7];
  const float* b2   = (const float*)d_in[8];
  const float* w3   = (const float*)d_in[9];
  const float* b3   = (const float*)d_in[10];
  float* out = (float*)d_out;

  dim3 grid(BATCH / ROWS);  // 256 blocks -> 1 per CU
  dim3 block(256);
  hipLaunchKernelGGL(gru_mfma, grid, block, 0, stream,
                     x, w_ih, w_hh, b_ih, b_hh, w1, b1, w2, b2, w3, b3, out);
}